// Round 5
// baseline (595.112 us; speedup 1.0000x reference)
//
#include <hip/hip_runtime.h>

typedef _Float16 f16;
typedef _Float16 f16x8 __attribute__((ext_vector_type(8)));
typedef _Float16 f16x4 __attribute__((ext_vector_type(4)));
typedef float    f32x4 __attribute__((ext_vector_type(4)));

static constexpr int NBATCH = 4;
static constexpr int NH     = 16;
static constexpr int SQ     = 2048;
static constexpr int DM     = 1024;
static constexpr int DHEAD  = 64;
static constexpr size_t TEL = (size_t)NBATCH * SQ * DM;   // 8388608 elems / tensor
static constexpr size_t WEL = (size_t)DM * DM;            // 1048576

// q pre-scale: (1/sqrt(64)) * log2(e)  -> scores land in log2 domain,
// exp(x) == exp2(x * log2e) computed by native v_exp_f32.
static constexpr float QSCALE = 0.125f * 1.4426950408889634f;

#define MFMA32(a, b, c) __builtin_amdgcn_mfma_f32_16x16x32_f16((a), (b), (c), 0, 0, 0)
#define MFMA16(a, b, c) __builtin_amdgcn_mfma_f32_16x16x16f16((a), (b), (c), 0, 0, 0)
#define EXP2(x) __builtin_amdgcn_exp2f(x)

// async global->LDS, 16B per lane; LDS dest is wave-uniform base + lane*16
#define GLOAD_LDS16(g, l)                                        \
    __builtin_amdgcn_global_load_lds(                            \
        (const __attribute__((address_space(1))) void*)(g),      \
        (__attribute__((address_space(3))) void*)(l), 16, 0, 0)

// ---------------------------------------------------------------------------
// fp32 -> fp16 conversion of Q,K,V,W (one pass, vectorized 32B->16B per thread)
__global__ __launch_bounds__(256) void cvt_kernel(
    const float* __restrict__ X0, const float* __restrict__ X1,
    const float* __restrict__ X2, const float* __restrict__ W,
    f16* __restrict__ y0, f16* __restrict__ y1,
    f16* __restrict__ y2, f16* __restrict__ yw)
{
    constexpr int CX = (int)(TEL / 8);   // 1048576 chunks of 8
    constexpr int CW = (int)(WEL / 8);   // 131072
    const int total = 3 * CX + CW;
    for (int c = blockIdx.x * blockDim.x + threadIdx.x; c < total;
         c += gridDim.x * blockDim.x) {
        const float* src; f16* dst; int off;
        if (c < CX)            { src = X0; dst = y0; off = c; }
        else if (c < 2 * CX)   { src = X1; dst = y1; off = c - CX; }
        else if (c < 3 * CX)   { src = X2; dst = y2; off = c - 2 * CX; }
        else                   { src = W;  dst = yw; off = c - 3 * CX; }
        const float* p = src + (size_t)off * 8;
        float4 lo = *(const float4*)p;
        float4 hi = *(const float4*)(p + 4);
        f16x8 v;
        v[0] = (f16)lo.x; v[1] = (f16)lo.y; v[2] = (f16)lo.z; v[3] = (f16)lo.w;
        v[4] = (f16)hi.x; v[5] = (f16)hi.y; v[6] = (f16)hi.z; v[7] = (f16)hi.w;
        *(f16x8*)(dst + (size_t)off * 8) = v;
    }
}

// ---------------------------------------------------------------------------
// Projection: P = X @ W^T + bias, all-fp16 operands, m97 structure:
// 128x128 tile, BK=32, double-buffered LDS via global_load_lds width-16,
// XOR swizzle c ^= (row>>1)&3 on 16B chunks. 3 blocks/CU resident.
//   which==0 (Q): store (p * QSCALE) as [bh][s][dh]
//   which==1 (K): store p            as [bh][s][dh]
//   which==2 (V): store p transposed as [bh][dh][s]
__global__ __launch_bounds__(256, 3) void proj_kernel(
    const f16* __restrict__ X0, const f16* __restrict__ X1,
    const f16* __restrict__ X2, const f16* __restrict__ W,
    const float* __restrict__ bias,
    f16* __restrict__ wq, f16* __restrict__ wk, f16* __restrict__ wv)
{
    alignas(16) __shared__ f16 la[2][128 * 32];   // 16 KB
    alignas(16) __shared__ f16 lb[2][128 * 32];   // 16 KB

    const int bid   = blockIdx.x;
    const int which = bid / 512;          // 0..2
    const int t0    = bid % 512;
    const int nb    = t0 >> 6;            // 0..7
    const int mb    = t0 & 63;            // 0..63
    const f16* __restrict__ X  = (which == 0) ? X0 : (which == 1) ? X1 : X2;
    const f16* __restrict__ A0 = X + (size_t)mb * 128 * DM;
    const f16* __restrict__ B0 = W + (size_t)nb * 128 * DM;

    const int tid  = threadIdx.x;
    const int wave = tid >> 6;
    const int lane = tid & 63;
    const int wr   = wave >> 1, wc = wave & 1;
    const int l16  = lane & 15, g = lane >> 4;
    const int m_base = mb * 128 + wr * 64;
    const int n_base = nb * 128 + wc * 64;

    auto stage = [&](int buf, int k0) {
        #pragma unroll
        for (int half = 0; half < 2; ++half) {
            const int idx = half * 256 + wave * 64 + lane;   // 16B-chunk index
            const int row = idx >> 2;
            const int sc  = (idx & 3) ^ ((row >> 1) & 3);
            const int db  = (half * 256 + wave * 64) * 8;    // wave-uniform
            GLOAD_LDS16(A0 + (size_t)row * DM + k0 + sc * 8, &la[buf][db]);
            GLOAD_LDS16(B0 + (size_t)row * DM + k0 + sc * 8, &lb[buf][db]);
        }
    };

    f32x4 acc[4][4];
    #pragma unroll
    for (int i = 0; i < 4; ++i)
        #pragma unroll
        for (int j = 0; j < 4; ++j)
            acc[i][j] = (f32x4){0.f, 0.f, 0.f, 0.f};

    stage(0, 0);
    __syncthreads();
    for (int t = 0; t < 32; ++t) {
        const int buf = t & 1;
        if (t < 31) stage(buf ^ 1, (t + 1) * 32);
        f16x8 af[4], bf[4];
        #pragma unroll
        for (int qs = 0; qs < 4; ++qs) {
            const int row = wr * 64 + qs * 16 + l16;
            af[qs] = *(const f16x8*)&la[buf][row * 32 +
                                             ((g ^ ((row >> 1) & 3)) << 3)];
        }
        #pragma unroll
        for (int ns = 0; ns < 4; ++ns) {
            const int row = wc * 64 + ns * 16 + l16;
            bf[ns] = *(const f16x8*)&lb[buf][row * 32 +
                                             ((g ^ ((row >> 1) & 3)) << 3)];
        }
        #pragma unroll
        for (int qs = 0; qs < 4; ++qs)
            #pragma unroll
            for (int ns = 0; ns < 4; ++ns)
                acc[qs][ns] = MFMA32(af[qs], bf[ns], acc[qs][ns]);
        __syncthreads();
    }

    const int    s_base = m_base & (SQ - 1);
    const int    b      = m_base >> 11;
    const int    h      = nb * 2 + wc;
    const size_t bh     = (size_t)b * NH + h;

    float bv[4];
    #pragma unroll
    for (int ns = 0; ns < 4; ++ns) bv[ns] = bias[n_base + ns * 16 + l16];

    if (which == 2) {
        #pragma unroll
        for (int qs = 0; qs < 4; ++qs)
            #pragma unroll
            for (int ns = 0; ns < 4; ++ns) {
                f16x4 pk;
                #pragma unroll
                for (int r = 0; r < 4; ++r) pk[r] = (f16)(acc[qs][ns][r] + bv[ns]);
                const int dh = ns * 16 + l16;
                const int s0 = s_base + qs * 16 + 4 * g;
                *(f16x4*)(wv + (bh * DHEAD + dh) * SQ + s0) = pk;
            }
    } else {
        f16* __restrict__ dst = (which == 0) ? wq : wk;
        const float sc = (which == 0) ? QSCALE : 1.0f;
        #pragma unroll
        for (int qs = 0; qs < 4; ++qs)
            #pragma unroll
            for (int ns = 0; ns < 4; ++ns)
                #pragma unroll
                for (int r = 0; r < 4; ++r) {
                    const int s  = s_base + qs * 16 + 4 * g + r;
                    const int dh = ns * 16 + l16;
                    dst[(bh * SQ + s) * DHEAD + dh] =
                        (f16)((acc[qs][ns][r] + bv[ns]) * sc);
                }
    }
}

// ---------------------------------------------------------------------------
// Attention with swapped QK^T: mfma(K,Q) -> thread holds S[kv=4g+r][q=l16].
// Sweep 1 (LDS-staged, barriers ok -- no global stores): QK + exp2 + row-sum
//         + unnormalized PV; out = O * (1/l), float4 stores.
// Sweep 2 (NO LDS, NO barriers): K frags direct from L2-hot global with
//         1-deep register prefetch; att = exp2(S)*linv, float4 streaming
//         stores that are never drained by a barrier.
__global__ __launch_bounds__(256, 4) void attn_kernel(
    const f16* __restrict__ wq, const f16* __restrict__ wk,
    const f16* __restrict__ wv,
    float* __restrict__ out, float* __restrict__ att)
{
    alignas(16) __shared__ f16 lk[2][64 * 64];    // 16 KB
    alignas(16) __shared__ f16 lv[2][64 * 64];    // 16 KB

    const int tid  = threadIdx.x;
    const int wave = tid >> 6;
    const int lane = tid & 63;
    const int l16  = lane & 15, g = lane >> 4;

    const int bid     = blockIdx.x;
    const int logical = (bid & 7) * 128 + (bid >> 3);
    const int bh      = logical >> 4;                 // 0..63
    const int q0      = (logical & 15) * 128 + wave * 32;

    const f16* __restrict__ qp = wq + (size_t)bh * SQ * DHEAD;
    const f16* __restrict__ kp = wk + (size_t)bh * SQ * DHEAD;
    const f16* __restrict__ vp = wv + (size_t)bh * DHEAD * SQ;
    float* __restrict__ attp = att + ((size_t)bh * SQ + q0) * SQ;
    const int b = bh >> 4, h = bh & 15;
    float* __restrict__ outp = out + ((size_t)b * SQ + q0) * DM + h * DHEAD;

    auto stage64 = [&](f16* dst0, const f16* gbase, int stride) {
        #pragma unroll
        for (int half = 0; half < 2; ++half) {
            const int idx = half * 256 + wave * 64 + lane;   // 16B-chunk index
            const int row = idx >> 3;
            const int sc  = (idx & 7) ^ (row & 7);           // involution
            GLOAD_LDS16(gbase + (size_t)row * stride + sc * 8,
                        dst0 + (size_t)(half * 256 + wave * 64) * 8);
        }
    };
    auto ldk8 = [&](int buf, int row, int c) -> f16x8 {
        return *(const f16x8*)&lk[buf][row * 64 + ((c ^ (row & 7)) << 3)];
    };
    auto ldv4 = [&](int buf, int row, int c_lin, int half8) -> f16x4 {
        return *(const f16x4*)&lv[buf][row * 64 + ((c_lin ^ (row & 7)) << 3) +
                                       half8 * 4];
    };

    f16x8 qf[2][2];
    #pragma unroll
    for (int qs = 0; qs < 2; ++qs)
        #pragma unroll
        for (int dhf = 0; dhf < 2; ++dhf)
            qf[qs][dhf] = *(const f16x8*)(qp + (size_t)(q0 + qs * 16 + l16) * DHEAD +
                                          dhf * 32 + g * 8);

    const f32x4 zero = (f32x4){0.f, 0.f, 0.f, 0.f};
    constexpr int NT = SQ / 64;   // 32 tiles

    // ---- sweep 1: QK + row-sum + unnormalized PV ----
    float accl[2] = {0.f, 0.f};
    f32x4 oacc[2][4];
    #pragma unroll
    for (int qs = 0; qs < 2; ++qs)
        #pragma unroll
        for (int ds = 0; ds < 4; ++ds) oacc[qs][ds] = zero;

    stage64(&lk[0][0], kp, DHEAD);
    stage64(&lv[0][0], vp, SQ);
    __syncthreads();
    for (int t = 0; t < NT; ++t) {
        const int buf = t & 1;
        if (t + 1 < NT) {
            stage64(&lk[buf ^ 1][0], kp + (size_t)(t + 1) * 64 * DHEAD, DHEAD);
            stage64(&lv[buf ^ 1][0], vp + (t + 1) * 64, SQ);
        }
        #pragma unroll
        for (int s16 = 0; s16 < 4; ++s16) {
            const int row = s16 * 16 + l16;
            f16x8 kf0 = ldk8(buf, row, g);
            f16x8 kf1 = ldk8(buf, row, 4 + g);
            f16x4 pb[2];
            #pragma unroll
            for (int qs = 0; qs < 2; ++qs) {
                f32x4 sc = MFMA32(kf0, qf[qs][0], zero);   // swapped: m=kv, n=q
                sc = MFMA32(kf1, qf[qs][1], sc);
                float e0 = EXP2(sc[0]), e1 = EXP2(sc[1]);
                float e2 = EXP2(sc[2]), e3 = EXP2(sc[3]);
                accl[qs] += (e0 + e1) + (e2 + e3);
                f16x4 p; p[0] = (f16)e0; p[1] = (f16)e1;
                p[2] = (f16)e2; p[3] = (f16)e3;
                pb[qs] = p;
            }
            #pragma unroll
            for (int ds = 0; ds < 4; ++ds) {
                f16x4 vf = ldv4(buf, ds * 16 + l16, s16 * 2 + (g >> 1), g & 1);
                oacc[0][ds] = MFMA16(vf, pb[0], oacc[0][ds]);
                oacc[1][ds] = MFMA16(vf, pb[1], oacc[1][ds]);
            }
        }
        __syncthreads();
    }

    // row sums: thread's q-row fixed (= qs*16+l16); reduce across g (xor 16,32)
    float linv[2];
    #pragma unroll
    for (int qs = 0; qs < 2; ++qs) {
        float v = accl[qs];
        v += __shfl_xor(v, 16, 64);
        v += __shfl_xor(v, 32, 64);
        linv[qs] = 1.f / v;
    }

    // ---- out store (O^T layout: thread = q-row qs*16+l16, dh = ds*16+4g+r) ----
    #pragma unroll
    for (int qs = 0; qs < 2; ++qs)
        #pragma unroll
        for (int ds = 0; ds < 4; ++ds) {
            float4 o;
            o.x = oacc[qs][ds][0] * linv[qs];
            o.y = oacc[qs][ds][1] * linv[qs];
            o.z = oacc[qs][ds][2] * linv[qs];
            o.w = oacc[qs][ds][3] * linv[qs];
            *(float4*)(outp + (size_t)(qs * 16 + l16) * DM + ds * 16 + 4 * g) = o;
        }

    // ---- sweep 2: att = exp2(S)*linv; K direct from global (L2-hot), no
    //      LDS, no barriers -> att stores free-run at write bandwidth ----
    {
        const f16* prow = kp + (size_t)l16 * DHEAD + g * 8;
        f16x8 nkf0 = *(const f16x8*)prow;
        f16x8 nkf1 = *(const f16x8*)(prow + 32);
        for (int kv16 = 0; kv16 < SQ / 16; ++kv16) {
            f16x8 kf0 = nkf0, kf1 = nkf1;
            if (kv16 + 1 < SQ / 16) {
                const f16* p = kp + (size_t)((kv16 + 1) * 16 + l16) * DHEAD + g * 8;
                nkf0 = *(const f16x8*)p;
                nkf1 = *(const f16x8*)(p + 32);
            }
            #pragma unroll
            for (int qs = 0; qs < 2; ++qs) {
                f32x4 sc = MFMA32(kf0, qf[qs][0], zero);
                sc = MFMA32(kf1, qf[qs][1], sc);
                float4 a;
                a.x = EXP2(sc[0]) * linv[qs];
                a.y = EXP2(sc[1]) * linv[qs];
                a.z = EXP2(sc[2]) * linv[qs];
                a.w = EXP2(sc[3]) * linv[qs];
                *(float4*)(attp + (size_t)(qs * 16 + l16) * SQ +
                           kv16 * 16 + 4 * g) = a;
            }
        }
    }
}

// ---------------------------------------------------------------------------
extern "C" void kernel_launch(void* const* d_in, const int* in_sizes, int n_in,
                              void* d_out, int out_size, void* d_ws, size_t ws_size,
                              hipStream_t stream) {
    const float* Q    = (const float*)d_in[0];
    const float* K    = (const float*)d_in[1];
    const float* V    = (const float*)d_in[2];
    const float* W    = (const float*)d_in[3];
    const float* bias = (const float*)d_in[4];

    f16* wq = (f16*)d_ws;            // [bh][s][dh] fp16, q pre-scaled by QSCALE
    f16* wk = wq + TEL;              // [bh][s][dh] fp16
    f16* wv = wk + TEL;              // [bh][dh][s] fp16 (transposed)

    float* out = (float*)d_out;      // [b][s][h*dh]
    float* att = out + TEL;          // [b][h][q][k]

    // fp16 copies of inputs live in the att region of d_out (1.07 GB):
    // written by cvt, read by proj, then fully overwritten by attn.
    f16* x0 = (f16*)att;
    f16* x1 = x0 + TEL;
    f16* x2 = x1 + TEL;
    f16* xw = x2 + TEL;              // + WEL

    cvt_kernel <<<2048, 256, 0, stream>>>(Q, K, V, W, x0, x1, x2, xw);
    proj_kernel<<<1536, 256, 0, stream>>>(x0, x1, x2, xw, bias, wq, wk, wv);
    attn_kernel<<<1024, 256, 0, stream>>>(wq, wk, wv, out, att);
}

// Round 6
// 443.795 us; speedup vs baseline: 1.3410x; 1.3410x over previous
//
#include <hip/hip_runtime.h>

typedef _Float16 f16;
typedef _Float16 f16x8 __attribute__((ext_vector_type(8)));
typedef _Float16 f16x4 __attribute__((ext_vector_type(4)));
typedef float    f32x4 __attribute__((ext_vector_type(4)));

static constexpr int NBATCH = 4;
static constexpr int NH     = 16;
static constexpr int SQ     = 2048;
static constexpr int DM     = 1024;
static constexpr int DHEAD  = 64;
static constexpr size_t TEL = (size_t)NBATCH * SQ * DM;   // 8388608 elems / tensor
static constexpr size_t WEL = (size_t)DM * DM;            // 1048576

// q pre-scale: (1/sqrt(64)) * log2(e)  -> scores land in log2 domain,
// exp(x) == exp2(x * log2e) via native v_exp_f32.
static constexpr float QSCALE = 0.125f * 1.4426950408889634f;

#define MFMA32(a, b, c) __builtin_amdgcn_mfma_f32_16x16x32_f16((a), (b), (c), 0, 0, 0)
#define MFMA16(a, b, c) __builtin_amdgcn_mfma_f32_16x16x16f16((a), (b), (c), 0, 0, 0)
#define EXP2(x) __builtin_amdgcn_exp2f(x)

// async global->LDS, 16B per lane; LDS dest is wave-uniform base + lane*16
#define GLOAD_LDS16(g, l)                                        \
    __builtin_amdgcn_global_load_lds(                            \
        (const __attribute__((address_space(1))) void*)(g),      \
        (__attribute__((address_space(3))) void*)(l), 16, 0, 0)

// ---------------------------------------------------------------------------
// fp32 -> fp16 conversion of Q,K,V,W (one pass, vectorized 32B->16B per thread)
__global__ __launch_bounds__(256) void cvt_kernel(
    const float* __restrict__ X0, const float* __restrict__ X1,
    const float* __restrict__ X2, const float* __restrict__ W,
    f16* __restrict__ y0, f16* __restrict__ y1,
    f16* __restrict__ y2, f16* __restrict__ yw)
{
    constexpr int CX = (int)(TEL / 8);   // 1048576 chunks of 8
    constexpr int CW = (int)(WEL / 8);   // 131072
    const int total = 3 * CX + CW;
    for (int c = blockIdx.x * blockDim.x + threadIdx.x; c < total;
         c += gridDim.x * blockDim.x) {
        const float* src; f16* dst; int off;
        if (c < CX)            { src = X0; dst = y0; off = c; }
        else if (c < 2 * CX)   { src = X1; dst = y1; off = c - CX; }
        else if (c < 3 * CX)   { src = X2; dst = y2; off = c - 2 * CX; }
        else                   { src = W;  dst = yw; off = c - 3 * CX; }
        const float* p = src + (size_t)off * 8;
        float4 lo = *(const float4*)p;
        float4 hi = *(const float4*)(p + 4);
        f16x8 v;
        v[0] = (f16)lo.x; v[1] = (f16)lo.y; v[2] = (f16)lo.z; v[3] = (f16)lo.w;
        v[4] = (f16)hi.x; v[5] = (f16)hi.y; v[6] = (f16)hi.z; v[7] = (f16)hi.w;
        *(f16x8*)(dst + (size_t)off * 8) = v;
    }
}

// ---------------------------------------------------------------------------
// Projection: P = X @ W^T + bias, all-fp16, m97 structure (128x128 tile,
// BK=32, double-buffered global_load_lds, XOR swizzle on 16B chunks).
// QK=true  (grid 1024): which = bid>>9 selects Q or K source/dst. MFMA
//   operands SWAPPED -> acc rows = dh(4g+r), cols = s(l16): epilogue packs
//   4 consecutive dh into f16x4 stores to [bh][s][dh] (16 stores vs 64).
//   Q gets QSCALE folded in.
// QK=false (grid 512): normal operand order; V stored transposed [bh][dh][s]
//   (r = 4 consecutive s packs into f16x4).
template <bool QK>
__global__ __launch_bounds__(256, 2) void proj_kernel(
    const f16* __restrict__ X0, const f16* __restrict__ X1,
    const f16* __restrict__ W, const float* __restrict__ bias,
    f16* __restrict__ d0, f16* __restrict__ d1)
{
    alignas(16) __shared__ f16 la[2][128 * 32];   // 16 KB
    alignas(16) __shared__ f16 lb[2][128 * 32];   // 16 KB

    const int bid   = blockIdx.x;
    const int which = QK ? (bid >> 9) : 0;        // 0..1 (QK) / 0 (V)
    const int t0    = bid & 511;
    const int nb    = t0 >> 6;            // 0..7
    const int mb    = t0 & 63;            // 0..63
    const f16* __restrict__ X  = (QK && which) ? X1 : X0;
    const f16* __restrict__ A0 = X + (size_t)mb * 128 * DM;
    const f16* __restrict__ B0 = W + (size_t)nb * 128 * DM;

    const int tid  = threadIdx.x;
    const int wave = tid >> 6;
    const int lane = tid & 63;
    const int wr   = wave >> 1, wc = wave & 1;
    const int l16  = lane & 15, g = lane >> 4;
    const int m_base = mb * 128 + wr * 64;
    const int n_base = nb * 128 + wc * 64;

    auto stage = [&](int buf, int k0) {
        #pragma unroll
        for (int half = 0; half < 2; ++half) {
            const int idx = half * 256 + wave * 64 + lane;   // 16B-chunk index
            const int row = idx >> 2;
            const int sc  = (idx & 3) ^ ((row >> 1) & 3);
            const int db  = (half * 256 + wave * 64) * 8;    // wave-uniform
            GLOAD_LDS16(A0 + (size_t)row * DM + k0 + sc * 8, &la[buf][db]);
            GLOAD_LDS16(B0 + (size_t)row * DM + k0 + sc * 8, &lb[buf][db]);
        }
    };

    f32x4 acc[4][4];
    #pragma unroll
    for (int i = 0; i < 4; ++i)
        #pragma unroll
        for (int j = 0; j < 4; ++j)
            acc[i][j] = (f32x4){0.f, 0.f, 0.f, 0.f};

    stage(0, 0);
    __syncthreads();
    for (int t = 0; t < 32; ++t) {
        const int buf = t & 1;
        if (t < 31) stage(buf ^ 1, (t + 1) * 32);
        f16x8 af[4], bf[4];
        #pragma unroll
        for (int qs = 0; qs < 4; ++qs) {
            const int row = wr * 64 + qs * 16 + l16;
            af[qs] = *(const f16x8*)&la[buf][row * 32 +
                                             ((g ^ ((row >> 1) & 3)) << 3)];
        }
        #pragma unroll
        for (int ns = 0; ns < 4; ++ns) {
            const int row = wc * 64 + ns * 16 + l16;
            bf[ns] = *(const f16x8*)&lb[buf][row * 32 +
                                             ((g ^ ((row >> 1) & 3)) << 3)];
        }
        #pragma unroll
        for (int qs = 0; qs < 4; ++qs)
            #pragma unroll
            for (int ns = 0; ns < 4; ++ns)
                acc[qs][ns] = QK ? MFMA32(bf[ns], af[qs], acc[qs][ns])
                                 : MFMA32(af[qs], bf[ns], acc[qs][ns]);
        __syncthreads();
    }

    const int    s_base = m_base & (SQ - 1);
    const int    b      = m_base >> 11;
    const int    h      = nb * 2 + wc;
    const size_t bh     = (size_t)b * NH + h;

    if (QK) {
        // acc[qs][ns][r]: row = dh = ns*16+4g+r, col = s = s_base+qs*16+l16
        f16* __restrict__ dst = which ? d1 : d0;
        const float sc = (which == 0) ? QSCALE : 1.0f;
        #pragma unroll
        for (int qs = 0; qs < 4; ++qs) {
            const int s = s_base + qs * 16 + l16;
            #pragma unroll
            for (int ns = 0; ns < 4; ++ns) {
                float4 bb = *(const float4*)&bias[n_base + ns * 16 + 4 * g];
                f16x4 pk;
                pk[0] = (f16)((acc[qs][ns][0] + bb.x) * sc);
                pk[1] = (f16)((acc[qs][ns][1] + bb.y) * sc);
                pk[2] = (f16)((acc[qs][ns][2] + bb.z) * sc);
                pk[3] = (f16)((acc[qs][ns][3] + bb.w) * sc);
                *(f16x4*)(dst + (bh * SQ + s) * DHEAD + ns * 16 + 4 * g) = pk;
            }
        }
    } else {
        // acc[qs][ns][r]: row = s = s_base+qs*16+4g+r, col = dh = ns*16+l16
        float bv[4];
        #pragma unroll
        for (int ns = 0; ns < 4; ++ns) bv[ns] = bias[n_base + ns * 16 + l16];
        #pragma unroll
        for (int qs = 0; qs < 4; ++qs)
            #pragma unroll
            for (int ns = 0; ns < 4; ++ns) {
                f16x4 pk;
                #pragma unroll
                for (int r = 0; r < 4; ++r) pk[r] = (f16)(acc[qs][ns][r] + bv[ns]);
                const int dh = ns * 16 + l16;
                const int s0 = s_base + qs * 16 + 4 * g;
                *(f16x4*)(d0 + (bh * DHEAD + dh) * SQ + s0) = pk;
            }
    }
}

// ---------------------------------------------------------------------------
// Attention with swapped QK^T: mfma(K,Q) -> thread holds S[kv=4g+r][q=l16].
// Sweep 1: LDS-staged K+V, QK + exp2 + row-sum + unnormalized PV (P fp16
//          direct from regs as 16x16x16 B-operand); O*(1/l), float4 stores.
// Sweep 2: LDS-staged K (double-buffered, deep global_load_lds pipeline),
//          QK recompute + exp2*linv -> float4 att stores.
__global__ __launch_bounds__(256, 4) void attn_kernel(
    const f16* __restrict__ wq, const f16* __restrict__ wk,
    const f16* __restrict__ wv,
    float* __restrict__ out, float* __restrict__ att)
{
    alignas(16) __shared__ f16 lk[2][64 * 64];    // 16 KB
    alignas(16) __shared__ f16 lv[2][64 * 64];    // 16 KB

    const int tid  = threadIdx.x;
    const int wave = tid >> 6;
    const int lane = tid & 63;
    const int l16  = lane & 15, g = lane >> 4;

    const int bid     = blockIdx.x;
    const int logical = (bid & 7) * 128 + (bid >> 3);
    const int bh      = logical >> 4;                 // 0..63
    const int q0      = (logical & 15) * 128 + wave * 32;

    const f16* __restrict__ qp = wq + (size_t)bh * SQ * DHEAD;
    const f16* __restrict__ kp = wk + (size_t)bh * SQ * DHEAD;
    const f16* __restrict__ vp = wv + (size_t)bh * DHEAD * SQ;
    float* __restrict__ attp = att + ((size_t)bh * SQ + q0) * SQ;
    const int b = bh >> 4, h = bh & 15;
    float* __restrict__ outp = out + ((size_t)b * SQ + q0) * DM + h * DHEAD;

    auto stage64 = [&](f16* dst0, const f16* gbase, int stride) {
        #pragma unroll
        for (int half = 0; half < 2; ++half) {
            const int idx = half * 256 + wave * 64 + lane;   // 16B-chunk index
            const int row = idx >> 3;
            const int sc  = (idx & 7) ^ (row & 7);           // involution
            GLOAD_LDS16(gbase + (size_t)row * stride + sc * 8,
                        dst0 + (size_t)(half * 256 + wave * 64) * 8);
        }
    };
    auto ldk8 = [&](int buf, int row, int c) -> f16x8 {
        return *(const f16x8*)&lk[buf][row * 64 + ((c ^ (row & 7)) << 3)];
    };
    auto ldv4 = [&](int buf, int row, int c_lin, int half8) -> f16x4 {
        return *(const f16x4*)&lv[buf][row * 64 + ((c_lin ^ (row & 7)) << 3) +
                                       half8 * 4];
    };

    f16x8 qf[2][2];
    #pragma unroll
    for (int qs = 0; qs < 2; ++qs)
        #pragma unroll
        for (int dhf = 0; dhf < 2; ++dhf)
            qf[qs][dhf] = *(const f16x8*)(qp + (size_t)(q0 + qs * 16 + l16) * DHEAD +
                                          dhf * 32 + g * 8);

    const f32x4 zero = (f32x4){0.f, 0.f, 0.f, 0.f};
    constexpr int NT = SQ / 64;   // 32 tiles

    // ---- sweep 1: QK + row-sum + unnormalized PV ----
    float accl[2] = {0.f, 0.f};
    f32x4 oacc[2][4];
    #pragma unroll
    for (int qs = 0; qs < 2; ++qs)
        #pragma unroll
        for (int ds = 0; ds < 4; ++ds) oacc[qs][ds] = zero;

    stage64(&lk[0][0], kp, DHEAD);
    stage64(&lv[0][0], vp, SQ);
    __syncthreads();
    for (int t = 0; t < NT; ++t) {
        const int buf = t & 1;
        if (t + 1 < NT) {
            stage64(&lk[buf ^ 1][0], kp + (size_t)(t + 1) * 64 * DHEAD, DHEAD);
            stage64(&lv[buf ^ 1][0], vp + (t + 1) * 64, SQ);
        }
        #pragma unroll
        for (int s16 = 0; s16 < 4; ++s16) {
            const int row = s16 * 16 + l16;
            f16x8 kf0 = ldk8(buf, row, g);
            f16x8 kf1 = ldk8(buf, row, 4 + g);
            f16x4 pb[2];
            #pragma unroll
            for (int qs = 0; qs < 2; ++qs) {
                f32x4 sc = MFMA32(kf0, qf[qs][0], zero);   // swapped: m=kv, n=q
                sc = MFMA32(kf1, qf[qs][1], sc);
                float e0 = EXP2(sc[0]), e1 = EXP2(sc[1]);
                float e2 = EXP2(sc[2]), e3 = EXP2(sc[3]);
                accl[qs] += (e0 + e1) + (e2 + e3);
                f16x4 p; p[0] = (f16)e0; p[1] = (f16)e1;
                p[2] = (f16)e2; p[3] = (f16)e3;
                pb[qs] = p;
            }
            #pragma unroll
            for (int ds = 0; ds < 4; ++ds) {
                f16x4 vf = ldv4(buf, ds * 16 + l16, s16 * 2 + (g >> 1), g & 1);
                oacc[0][ds] = MFMA16(vf, pb[0], oacc[0][ds]);
                oacc[1][ds] = MFMA16(vf, pb[1], oacc[1][ds]);
            }
        }
        __syncthreads();
    }

    // row sums: thread's q-row fixed (= qs*16+l16); reduce across g (xor 16,32)
    float linv[2];
    #pragma unroll
    for (int qs = 0; qs < 2; ++qs) {
        float v = accl[qs];
        v += __shfl_xor(v, 16, 64);
        v += __shfl_xor(v, 32, 64);
        linv[qs] = 1.f / v;
    }

    // ---- out store (O^T layout: thread = q-row qs*16+l16, dh = ds*16+4g+r) ----
    #pragma unroll
    for (int qs = 0; qs < 2; ++qs)
        #pragma unroll
        for (int ds = 0; ds < 4; ++ds) {
            float4 o;
            o.x = oacc[qs][ds][0] * linv[qs];
            o.y = oacc[qs][ds][1] * linv[qs];
            o.z = oacc[qs][ds][2] * linv[qs];
            o.w = oacc[qs][ds][3] * linv[qs];
            *(float4*)(outp + (size_t)(qs * 16 + l16) * DM + ds * 16 + 4 * g) = o;
        }

    // ---- sweep 2: att = exp2(S)*linv, float4 streaming stores (LDS K) ----
    stage64(&lk[0][0], kp, DHEAD);
    __syncthreads();
    for (int t = 0; t < NT; ++t) {
        const int buf = t & 1;
        const int kv0 = t * 64;
        if (t + 1 < NT)
            stage64(&lk[buf ^ 1][0], kp + (size_t)(t + 1) * 64 * DHEAD, DHEAD);
        #pragma unroll
        for (int s16 = 0; s16 < 4; ++s16) {
            const int row = s16 * 16 + l16;
            f16x8 kf0 = ldk8(buf, row, g);
            f16x8 kf1 = ldk8(buf, row, 4 + g);
            #pragma unroll
            for (int qs = 0; qs < 2; ++qs) {
                f32x4 sc = MFMA32(kf0, qf[qs][0], zero);
                sc = MFMA32(kf1, qf[qs][1], sc);
                float4 a;
                a.x = EXP2(sc[0]) * linv[qs];
                a.y = EXP2(sc[1]) * linv[qs];
                a.z = EXP2(sc[2]) * linv[qs];
                a.w = EXP2(sc[3]) * linv[qs];
                *(float4*)(attp + (size_t)(qs * 16 + l16) * SQ + kv0 +
                           s16 * 16 + 4 * g) = a;
            }
        }
        __syncthreads();
    }
}

// ---------------------------------------------------------------------------
extern "C" void kernel_launch(void* const* d_in, const int* in_sizes, int n_in,
                              void* d_out, int out_size, void* d_ws, size_t ws_size,
                              hipStream_t stream) {
    const float* Q    = (const float*)d_in[0];
    const float* K    = (const float*)d_in[1];
    const float* V    = (const float*)d_in[2];
    const float* W    = (const float*)d_in[3];
    const float* bias = (const float*)d_in[4];

    f16* wq = (f16*)d_ws;            // [bh][s][dh] fp16, q pre-scaled by QSCALE
    f16* wk = wq + TEL;              // [bh][s][dh] fp16
    f16* wv = wk + TEL;              // [bh][dh][s] fp16 (transposed)

    float* out = (float*)d_out;      // [b][s][h*dh]
    float* att = out + TEL;          // [b][h][q][k]

    // fp16 copies of inputs live in the att region of d_out (1.07 GB):
    // written by cvt, read by proj, then fully overwritten by attn.
    f16* x0 = (f16*)att;
    f16* x1 = x0 + TEL;
    f16* x2 = x1 + TEL;
    f16* xw = x2 + TEL;              // + WEL

    cvt_kernel <<<2048, 256, 0, stream>>>(Q, K, V, W, x0, x1, x2, xw);
    proj_kernel<true ><<<1024, 256, 0, stream>>>(x0, x1, xw, bias, wq, wk);
    proj_kernel<false><<< 512, 256, 0, stream>>>(x2, nullptr, xw, bias, wv, nullptr);
    attn_kernel<<<1024, 256, 0, stream>>>(wq, wk, wv, out, att);
}

// Round 7
// 435.600 us; speedup vs baseline: 1.3662x; 1.0188x over previous
//
#include <hip/hip_runtime.h>

typedef _Float16 f16;
typedef _Float16 f16x8 __attribute__((ext_vector_type(8)));
typedef _Float16 f16x4 __attribute__((ext_vector_type(4)));
typedef float    f32x4 __attribute__((ext_vector_type(4)));

static constexpr int NBATCH = 4;
static constexpr int NH     = 16;
static constexpr int SQ     = 2048;
static constexpr int DM     = 1024;
static constexpr int DHEAD  = 64;
static constexpr size_t TEL = (size_t)NBATCH * SQ * DM;   // 8388608 elems / tensor
static constexpr size_t WEL = (size_t)DM * DM;            // 1048576

// q pre-scale: (1/sqrt(64)) * log2(e)  -> scores land in log2 domain,
// exp(x) == exp2(x * log2e) via native v_exp_f32.
static constexpr float QSCALE = 0.125f * 1.4426950408889634f;

#define MFMA32(a, b, c) __builtin_amdgcn_mfma_f32_16x16x32_f16((a), (b), (c), 0, 0, 0)
#define EXP2(x) __builtin_amdgcn_exp2f(x)

// async global->LDS, 16B per lane; LDS dest is wave-uniform base + lane*16
#define GLOAD_LDS16(g, l)                                        \
    __builtin_amdgcn_global_load_lds(                            \
        (const __attribute__((address_space(1))) void*)(g),      \
        (__attribute__((address_space(3))) void*)(l), 16, 0, 0)

// ---------------------------------------------------------------------------
// fp32 -> fp16 conversion of Q,K,V,W (one pass, vectorized 32B->16B per thread)
__global__ __launch_bounds__(256) void cvt_kernel(
    const float* __restrict__ X0, const float* __restrict__ X1,
    const float* __restrict__ X2, const float* __restrict__ W,
    f16* __restrict__ y0, f16* __restrict__ y1,
    f16* __restrict__ y2, f16* __restrict__ yw)
{
    constexpr int CX = (int)(TEL / 8);   // 1048576 chunks of 8
    constexpr int CW = (int)(WEL / 8);   // 131072
    const int total = 3 * CX + CW;
    for (int c = blockIdx.x * blockDim.x + threadIdx.x; c < total;
         c += gridDim.x * blockDim.x) {
        const float* src; f16* dst; int off;
        if (c < CX)            { src = X0; dst = y0; off = c; }
        else if (c < 2 * CX)   { src = X1; dst = y1; off = c - CX; }
        else if (c < 3 * CX)   { src = X2; dst = y2; off = c - 2 * CX; }
        else                   { src = W;  dst = yw; off = c - 3 * CX; }
        const float* p = src + (size_t)off * 8;
        float4 lo = *(const float4*)p;
        float4 hi = *(const float4*)(p + 4);
        f16x8 v;
        v[0] = (f16)lo.x; v[1] = (f16)lo.y; v[2] = (f16)lo.z; v[3] = (f16)lo.w;
        v[4] = (f16)hi.x; v[5] = (f16)hi.y; v[6] = (f16)hi.z; v[7] = (f16)hi.w;
        *(f16x8*)(dst + (size_t)off * 8) = v;
    }
}

// ---------------------------------------------------------------------------
// Projection: P = X @ W^T + bias, all-fp16, m97 structure (128x128 tile,
// BK=32, double-buffered global_load_lds, XOR swizzle on 16B chunks).
// QK=true  (grid 1024): which = bid>>9 selects Q or K. MFMA operands swapped
//   -> epilogue packs 4 consecutive dh into f16x4 stores to [bh][s][dh].
//   Q gets QSCALE folded in.
// QK=false (grid 512): normal order; V stored transposed [bh][dh][s].
template <bool QK>
__global__ __launch_bounds__(256, 2) void proj_kernel(
    const f16* __restrict__ X0, const f16* __restrict__ X1,
    const f16* __restrict__ W, const float* __restrict__ bias,
    f16* __restrict__ d0, f16* __restrict__ d1)
{
    alignas(16) __shared__ f16 la[2][128 * 32];   // 16 KB
    alignas(16) __shared__ f16 lb[2][128 * 32];   // 16 KB

    const int bid   = blockIdx.x;
    const int which = QK ? (bid >> 9) : 0;        // 0..1 (QK) / 0 (V)
    const int t0    = bid & 511;
    const int nb    = t0 >> 6;            // 0..7
    const int mb    = t0 & 63;            // 0..63
    const f16* __restrict__ X  = (QK && which) ? X1 : X0;
    const f16* __restrict__ A0 = X + (size_t)mb * 128 * DM;
    const f16* __restrict__ B0 = W + (size_t)nb * 128 * DM;

    const int tid  = threadIdx.x;
    const int wave = tid >> 6;
    const int lane = tid & 63;
    const int wr   = wave >> 1, wc = wave & 1;
    const int l16  = lane & 15, g = lane >> 4;
    const int m_base = mb * 128 + wr * 64;
    const int n_base = nb * 128 + wc * 64;

    auto stage = [&](int buf, int k0) {
        #pragma unroll
        for (int half = 0; half < 2; ++half) {
            const int idx = half * 256 + wave * 64 + lane;   // 16B-chunk index
            const int row = idx >> 2;
            const int sc  = (idx & 3) ^ ((row >> 1) & 3);
            const int db  = (half * 256 + wave * 64) * 8;    // wave-uniform
            GLOAD_LDS16(A0 + (size_t)row * DM + k0 + sc * 8, &la[buf][db]);
            GLOAD_LDS16(B0 + (size_t)row * DM + k0 + sc * 8, &lb[buf][db]);
        }
    };

    f32x4 acc[4][4];
    #pragma unroll
    for (int i = 0; i < 4; ++i)
        #pragma unroll
        for (int j = 0; j < 4; ++j)
            acc[i][j] = (f32x4){0.f, 0.f, 0.f, 0.f};

    stage(0, 0);
    __syncthreads();
    for (int t = 0; t < 32; ++t) {
        const int buf = t & 1;
        if (t < 31) stage(buf ^ 1, (t + 1) * 32);
        f16x8 af[4], bf[4];
        #pragma unroll
        for (int qs = 0; qs < 4; ++qs) {
            const int row = wr * 64 + qs * 16 + l16;
            af[qs] = *(const f16x8*)&la[buf][row * 32 +
                                             ((g ^ ((row >> 1) & 3)) << 3)];
        }
        #pragma unroll
        for (int ns = 0; ns < 4; ++ns) {
            const int row = wc * 64 + ns * 16 + l16;
            bf[ns] = *(const f16x8*)&lb[buf][row * 32 +
                                             ((g ^ ((row >> 1) & 3)) << 3)];
        }
        #pragma unroll
        for (int qs = 0; qs < 4; ++qs)
            #pragma unroll
            for (int ns = 0; ns < 4; ++ns)
                acc[qs][ns] = QK ? MFMA32(bf[ns], af[qs], acc[qs][ns])
                                 : MFMA32(af[qs], bf[ns], acc[qs][ns]);
        __syncthreads();
    }

    const int    s_base = m_base & (SQ - 1);
    const int    b      = m_base >> 11;
    const int    h      = nb * 2 + wc;
    const size_t bh     = (size_t)b * NH + h;

    if (QK) {
        // acc[qs][ns][r]: row = dh = ns*16+4g+r, col = s = s_base+qs*16+l16
        f16* __restrict__ dst = which ? d1 : d0;
        const float sc = (which == 0) ? QSCALE : 1.0f;
        #pragma unroll
        for (int qs = 0; qs < 4; ++qs) {
            const int s = s_base + qs * 16 + l16;
            #pragma unroll
            for (int ns = 0; ns < 4; ++ns) {
                float4 bb = *(const float4*)&bias[n_base + ns * 16 + 4 * g];
                f16x4 pk;
                pk[0] = (f16)((acc[qs][ns][0] + bb.x) * sc);
                pk[1] = (f16)((acc[qs][ns][1] + bb.y) * sc);
                pk[2] = (f16)((acc[qs][ns][2] + bb.z) * sc);
                pk[3] = (f16)((acc[qs][ns][3] + bb.w) * sc);
                *(f16x4*)(dst + (bh * SQ + s) * DHEAD + ns * 16 + 4 * g) = pk;
            }
        }
    } else {
        // acc[qs][ns][r]: row = s = s_base+qs*16+4g+r, col = dh = ns*16+l16
        float bv[4];
        #pragma unroll
        for (int ns = 0; ns < 4; ++ns) bv[ns] = bias[n_base + ns * 16 + l16];
        #pragma unroll
        for (int qs = 0; qs < 4; ++qs)
            #pragma unroll
            for (int ns = 0; ns < 4; ++ns) {
                f16x4 pk;
                #pragma unroll
                for (int r = 0; r < 4; ++r) pk[r] = (f16)(acc[qs][ns][r] + bv[ns]);
                const int dh = ns * 16 + l16;
                const int s0 = s_base + qs * 16 + 4 * g;
                *(f16x4*)(d0 + (bh * DHEAD + dh) * SQ + s0) = pk;
            }
    }
}

// ---------------------------------------------------------------------------
// Attention with swapped QK^T: mfma(K,Q) -> thread holds S[kv=4g+r][q=l16].
// Sweep 1 (re-sequenced sync: vmcnt(0) + RAW s_barrier + stage-AFTER-barrier,
//   one barrier/tile -- a wave never waits on a load issued this iteration):
//   QK + exp2 + row-sum + unnormalized PV via MFMA32 (paired granules);
//   O*(1/l), float4 out stores.
// Sweep 2 (known-good __syncthreads pipeline): QK recompute + exp2*linv ->
//   float4 att streaming stores.
__global__ __launch_bounds__(256, 4) void attn_kernel(
    const f16* __restrict__ wq, const f16* __restrict__ wk,
    const f16* __restrict__ wv,
    float* __restrict__ out, float* __restrict__ att)
{
    alignas(16) __shared__ f16 lk[2][64 * 64];    // 16 KB
    alignas(16) __shared__ f16 lv[2][64 * 64];    // 16 KB

    const int tid  = threadIdx.x;
    const int wave = tid >> 6;
    const int lane = tid & 63;
    const int l16  = lane & 15, g = lane >> 4;

    const int bid     = blockIdx.x;
    const int logical = (bid & 7) * 128 + (bid >> 3);
    const int bh      = logical >> 4;                 // 0..63
    const int q0      = (logical & 15) * 128 + wave * 32;

    const f16* __restrict__ qp = wq + (size_t)bh * SQ * DHEAD;
    const f16* __restrict__ kp = wk + (size_t)bh * SQ * DHEAD;
    const f16* __restrict__ vp = wv + (size_t)bh * DHEAD * SQ;
    float* __restrict__ attp = att + ((size_t)bh * SQ + q0) * SQ;
    const int b = bh >> 4, h = bh & 15;
    float* __restrict__ outp = out + ((size_t)b * SQ + q0) * DM + h * DHEAD;

    auto stage64 = [&](f16* dst0, const f16* gbase, int stride) {
        #pragma unroll
        for (int half = 0; half < 2; ++half) {
            const int idx = half * 256 + wave * 64 + lane;   // 16B-chunk index
            const int row = idx >> 3;
            const int sc  = (idx & 7) ^ (row & 7);           // involution
            GLOAD_LDS16(gbase + (size_t)row * stride + sc * 8,
                        dst0 + (size_t)(half * 256 + wave * 64) * 8);
        }
    };
    auto ldk8 = [&](int buf, int row, int c) -> f16x8 {
        return *(const f16x8*)&lk[buf][row * 64 + ((c ^ (row & 7)) << 3)];
    };
    auto ldv4 = [&](int buf, int row, int c_lin, int half8) -> f16x4 {
        return *(const f16x4*)&lv[buf][row * 64 + ((c_lin ^ (row & 7)) << 3) +
                                       half8 * 4];
    };

    f16x8 qf[2][2];
    #pragma unroll
    for (int qs = 0; qs < 2; ++qs)
        #pragma unroll
        for (int dhf = 0; dhf < 2; ++dhf)
            qf[qs][dhf] = *(const f16x8*)(qp + (size_t)(q0 + qs * 16 + l16) * DHEAD +
                                          dhf * 32 + g * 8);

    const f32x4 zero = (f32x4){0.f, 0.f, 0.f, 0.f};
    constexpr int NT = SQ / 64;   // 32 tiles

    // ---- sweep 1: QK + row-sum + unnormalized PV (MFMA32 pairs) ----
    float accl[2] = {0.f, 0.f};
    f32x4 oacc[2][4];
    #pragma unroll
    for (int qs = 0; qs < 2; ++qs)
        #pragma unroll
        for (int ds = 0; ds < 4; ++ds) oacc[qs][ds] = zero;

    stage64(&lk[0][0], kp, DHEAD);
    stage64(&lv[0][0], vp, SQ);
    for (int t = 0; t < NT; ++t) {
        const int buf = t & 1;
        // granule t is the only VMEM in flight -> this waits exactly it
        asm volatile("s_waitcnt vmcnt(0)" ::: "memory");
        __builtin_amdgcn_s_barrier();
        if (t + 1 < NT) {     // stage AFTER barrier: overwrites slot t-1,
                              // which every wave finished reading pre-barrier
            stage64(&lk[buf ^ 1][0], kp + (size_t)(t + 1) * 64 * DHEAD, DHEAD);
            stage64(&lv[buf ^ 1][0], vp + (t + 1) * 64, SQ);
        }
        #pragma unroll
        for (int p = 0; p < 2; ++p) {          // 32-kv granule pair
            f16x8 pb8[2];
            #pragma unroll
            for (int hh = 0; hh < 2; ++hh) {   // 16-kv halves
                const int row = p * 32 + hh * 16 + l16;
                f16x8 kf0 = ldk8(buf, row, g);
                f16x8 kf1 = ldk8(buf, row, 4 + g);
                #pragma unroll
                for (int qs = 0; qs < 2; ++qs) {
                    f32x4 sc = MFMA32(kf0, qf[qs][0], zero);   // m=kv, n=q
                    sc = MFMA32(kf1, qf[qs][1], sc);
                    float e0 = EXP2(sc[0]), e1 = EXP2(sc[1]);
                    float e2 = EXP2(sc[2]), e3 = EXP2(sc[3]);
                    accl[qs] += (e0 + e1) + (e2 + e3);
                    pb8[qs][hh * 4 + 0] = (f16)e0;
                    pb8[qs][hh * 4 + 1] = (f16)e1;
                    pb8[qs][hh * 4 + 2] = (f16)e2;
                    pb8[qs][hh * 4 + 3] = (f16)e3;
                }
            }
            // PV: A half j <-> kv p*32 + {4g+j | 16+4g+(j-4)}, matching pb8
            #pragma unroll
            for (int ds = 0; ds < 4; ++ds) {
                const int vrow = ds * 16 + l16;
                f16x4 va = ldv4(buf, vrow, p * 4 + (g >> 1), g & 1);
                f16x4 vb = ldv4(buf, vrow, p * 4 + 2 + (g >> 1), g & 1);
                f16x8 vf8;
                vf8[0] = va[0]; vf8[1] = va[1]; vf8[2] = va[2]; vf8[3] = va[3];
                vf8[4] = vb[0]; vf8[5] = vb[1]; vf8[6] = vb[2]; vf8[7] = vb[3];
                oacc[0][ds] = MFMA32(vf8, pb8[0], oacc[0][ds]);
                oacc[1][ds] = MFMA32(vf8, pb8[1], oacc[1][ds]);
            }
        }
    }

    // row sums: thread's q-row fixed (= qs*16+l16); reduce across g (xor 16,32)
    float linv[2];
    #pragma unroll
    for (int qs = 0; qs < 2; ++qs) {
        float v = accl[qs];
        v += __shfl_xor(v, 16, 64);
        v += __shfl_xor(v, 32, 64);
        linv[qs] = 1.f / v;
    }

    // ---- out store (O^T layout: thread = q-row qs*16+l16, dh = ds*16+4g+r) ----
    #pragma unroll
    for (int qs = 0; qs < 2; ++qs)
        #pragma unroll
        for (int ds = 0; ds < 4; ++ds) {
            float4 o;
            o.x = oacc[qs][ds][0] * linv[qs];
            o.y = oacc[qs][ds][1] * linv[qs];
            o.z = oacc[qs][ds][2] * linv[qs];
            o.w = oacc[qs][ds][3] * linv[qs];
            *(float4*)(outp + (size_t)(qs * 16 + l16) * DM + ds * 16 + 4 * g) = o;
        }

    // ---- sweep 2: att = exp2(S)*linv, float4 streaming stores (LDS K) ----
    stage64(&lk[0][0], kp, DHEAD);
    __syncthreads();
    for (int t = 0; t < NT; ++t) {
        const int buf = t & 1;
        const int kv0 = t * 64;
        if (t + 1 < NT)
            stage64(&lk[buf ^ 1][0], kp + (size_t)(t + 1) * 64 * DHEAD, DHEAD);
        #pragma unroll
        for (int s16 = 0; s16 < 4; ++s16) {
            const int row = s16 * 16 + l16;
            f16x8 kf0 = ldk8(buf, row, g);
            f16x8 kf1 = ldk8(buf, row, 4 + g);
            #pragma unroll
            for (int qs = 0; qs < 2; ++qs) {
                f32x4 sc = MFMA32(kf0, qf[qs][0], zero);
                sc = MFMA32(kf1, qf[qs][1], sc);
                float4 a;
                a.x = EXP2(sc[0]) * linv[qs];
                a.y = EXP2(sc[1]) * linv[qs];
                a.z = EXP2(sc[2]) * linv[qs];
                a.w = EXP2(sc[3]) * linv[qs];
                *(float4*)(attp + (size_t)(qs * 16 + l16) * SQ + kv0 +
                           s16 * 16 + 4 * g) = a;
            }
        }
        __syncthreads();
    }
}

// ---------------------------------------------------------------------------
extern "C" void kernel_launch(void* const* d_in, const int* in_sizes, int n_in,
                              void* d_out, int out_size, void* d_ws, size_t ws_size,
                              hipStream_t stream) {
    const float* Q    = (const float*)d_in[0];
    const float* K    = (const float*)d_in[1];
    const float* V    = (const float*)d_in[2];
    const float* W    = (const float*)d_in[3];
    const float* bias = (const float*)d_in[4];

    f16* wq = (f16*)d_ws;            // [bh][s][dh] fp16, q pre-scaled by QSCALE
    f16* wk = wq + TEL;              // [bh][s][dh] fp16
    f16* wv = wk + TEL;              // [bh][dh][s] fp16 (transposed)

    float* out = (float*)d_out;      // [b][s][h*dh]
    float* att = out + TEL;          // [b][h][q][k]

    // fp16 copies of inputs live in the att region of d_out (1.07 GB):
    // written by cvt, read by proj, then fully overwritten by attn.
    f16* x0 = (f16*)att;
    f16* x1 = x0 + TEL;
    f16* x2 = x1 + TEL;
    f16* xw = x2 + TEL;              // + WEL

    cvt_kernel <<<2048, 256, 0, stream>>>(Q, K, V, W, x0, x1, x2, xw);
    proj_kernel<true ><<<1024, 256, 0, stream>>>(x0, x1, xw, bias, wq, wk);
    proj_kernel<false><<< 512, 256, 0, stream>>>(x2, nullptr, xw, bias, wv, nullptr);
    attn_kernel<<<1024, 256, 0, stream>>>(wq, wk, wv, out, att);
}